// Round 11
// baseline (245.615 us; speedup 1.0000x reference)
//
#include <hip/hip_runtime.h>
#include <hip/hip_bf16.h>
#include <hip/hip_cooperative_groups.h>

namespace cg = cooperative_groups;

typedef __attribute__((ext_vector_type(8))) short bf16x8;
typedef __attribute__((ext_vector_type(4))) float f32x4;

#define CAP 64   // fixed per-node edge slot capacity (deg>CAP -> exact fallback)
#define LDK 264

// fp32 -> bf16 (round-to-nearest-even), bit pattern as ushort
static __device__ inline unsigned short f2b(float f) {
    unsigned u = __float_as_uint(f);
    unsigned r = (u + 0x7FFFu + ((u >> 16) & 1u)) >> 16;
    return (unsigned short)r;
}
// packed bf16 pair -> two fp32
static __device__ inline float blo(unsigned u) { return __uint_as_float(u << 16); }
static __device__ inline float bhi(unsigned u) { return __uint_as_float(u & 0xFFFF0000u); }
// pack 4 fp32 -> 4 OCP e4m3 bytes
static __device__ inline unsigned pk_fp8x4(float a, float b, float c, float d) {
    int v = __builtin_amdgcn_cvt_pk_fp8_f32(a, b, 0, false);
    v = __builtin_amdgcn_cvt_pk_fp8_f32(c, d, v, true);
    return (unsigned)v;
}
static __device__ inline unsigned char f2f8(float v) {
    return (unsigned char)(__builtin_amdgcn_cvt_pk_fp8_f32(v, v, 0, false) & 0xFF);
}

// ===========================================================================
// Phase bodies (shared between mega-kernel and split fallback)
// ===========================================================================

// P0: zero cursor; x -> xb (bf16) + xf8 (fp8); weights -> wt[layer][n][k]
static __device__ void prep_phase(const float* __restrict__ x,
                                  unsigned short* __restrict__ xb,
                                  unsigned char* __restrict__ xf8,
                                  int* __restrict__ cursor,
                                  const float* __restrict__ W1l, const float* __restrict__ W1r,
                                  const float* __restrict__ W2l, const float* __restrict__ W2r,
                                  unsigned short* __restrict__ wt, int N, int T, int t0) {
    for (int i = t0; i < N; i += T) cursor[i] = 0;
    int n4 = N * 32;                       // N*128/4 float4 chunks
    for (int i = t0; i < n4; i += T) {
        float4 v = ((const float4*)x)[i];
        ushort4 o;
        o.x = f2b(v.x); o.y = f2b(v.y); o.z = f2b(v.z); o.w = f2b(v.w);
        ((ushort4*)xb)[i] = o;
        ((unsigned*)xf8)[i] = pk_fp8x4(v.x, v.y, v.z, v.w);
    }
    for (int id = t0; id < 65536; id += T) {   // wt[layer][n][k]
        int layer = id >> 15;
        int rem = id & 32767;
        int n = rem >> 8;
        int kk = rem & 255;
        const float* Wlp = layer ? W2l : W1l;
        const float* Wrp = layer ? W2r : W1r;
        float v = (kk < 128) ? Wlp[(size_t)kk * 128 + n]
                             : Wrp[(size_t)(kk - 128) * 128 + n];
        wt[(size_t)layer * 32768 + (size_t)n * 256 + kk] = f2b(v);
    }
}

// P1: XCD-sharded slot fill (shard = blockIdx&7 ~ XCD&7; each node's 128B
// slot line dirtied by one XCD -> single writeback). cursor[d] ends == deg(d).
static __device__ void fill_phase(const int* __restrict__ ei, int* __restrict__ cursor,
                                  unsigned short* __restrict__ edge16, int E, int N,
                                  int bid, int nblocks) {
    int s  = bid & 7;
    int ci = bid >> 3;
    int G  = nblocks >> 3;
    int npg = (N + 7) >> 3;
    int d_lo = s * npg;
    int d_hi = d_lo + npg; if (d_hi > N) d_hi = N;
    int C = (E + G - 1) / G;
    int e0 = ci * C;
    int e1 = e0 + C; if (e1 > E) e1 = E;
    for (int e = e0 + (int)threadIdx.x; e < e1; e += 256) {
        int d = ei[E + e];
        if (d < d_lo || d >= d_hi) continue;
        int src = ei[e];
        if ((unsigned)src >= (unsigned)N) src = 0;   // defensive
        int pos = atomicAdd(&cursor[d], 1);
        if (pos < CAP) edge16[(size_t)d * CAP + pos] = (unsigned short)src;
    }
}

// Aggregation: mean over fp8 in-neighbor rows, fp32 accumulate, bf16 out.
// One wave per node; lane = g*8+f: group g handles edge j+g, f covers 16B of
// the 128B fp8 row. shfl_xor reduce. deg>CAP -> exact full-scan fallback.
static __device__ void agg_phase(const unsigned char* __restrict__ in8,
                                 const int* __restrict__ cursor,
                                 const unsigned short* __restrict__ edge16,
                                 const int* __restrict__ ei,
                                 unsigned short* __restrict__ agg, int E, int N,
                                 int bid, int nblocks) {
    int wave = threadIdx.x >> 6;
    int lane = threadIdx.x & 63;
    int g = lane >> 3;
    int f = lane & 7;
    for (int base = bid * 4; base < N; base += nblocks * 4) {
        int node = base + wave;
        if (node >= N) continue;
        int deg = cursor[node];

        float acc[16];
        #pragma unroll
        for (int t = 0; t < 16; ++t) acc[t] = 0.f;

        if (deg <= CAP) {
            const unsigned short* basep = edge16 + (size_t)node * CAP;
            int idx = (lane < deg) ? (int)basep[lane] : 0;   // coalesced preload
            #pragma unroll 2
            for (int j = 0; j < deg; j += 8) {
                int e = j + g;
                int s = __shfl(idx, e & 63);
                if (e < deg) {
                    uint4 v = *(const uint4*)(in8 + (size_t)s * 128 + f * 16);
                    #pragma unroll
                    for (int w = 0; w < 4; ++w) {
                        unsigned dw = (&v.x)[w];
                        acc[w * 4 + 0] += __builtin_amdgcn_cvt_f32_fp8(dw, 0);
                        acc[w * 4 + 1] += __builtin_amdgcn_cvt_f32_fp8(dw, 1);
                        acc[w * 4 + 2] += __builtin_amdgcn_cvt_f32_fp8(dw, 2);
                        acc[w * 4 + 3] += __builtin_amdgcn_cvt_f32_fp8(dw, 3);
                    }
                }
            }
        } else {
            for (int j = 0; j < E; j += 8) {
                int e = j + g;
                bool act = (e < E) && (ei[E + e] == node);
                if (act) {
                    int s = ei[e];
                    if ((unsigned)s >= (unsigned)N) s = 0;
                    uint4 v = *(const uint4*)(in8 + (size_t)s * 128 + f * 16);
                    #pragma unroll
                    for (int w = 0; w < 4; ++w) {
                        unsigned dw = (&v.x)[w];
                        acc[w * 4 + 0] += __builtin_amdgcn_cvt_f32_fp8(dw, 0);
                        acc[w * 4 + 1] += __builtin_amdgcn_cvt_f32_fp8(dw, 1);
                        acc[w * 4 + 2] += __builtin_amdgcn_cvt_f32_fp8(dw, 2);
                        acc[w * 4 + 3] += __builtin_amdgcn_cvt_f32_fp8(dw, 3);
                    }
                }
            }
        }

        #pragma unroll
        for (int d = 8; d <= 32; d <<= 1) {
            #pragma unroll
            for (int t = 0; t < 16; ++t) acc[t] += __shfl_xor(acc[t], d);
        }

        if (g == 0) {
            float inv = 1.0f / (float)(deg > 1 ? deg : 1);
            uint4 o0, o1;
            o0.x = (unsigned)f2b(acc[0] * inv)  | ((unsigned)f2b(acc[1] * inv)  << 16);
            o0.y = (unsigned)f2b(acc[2] * inv)  | ((unsigned)f2b(acc[3] * inv)  << 16);
            o0.z = (unsigned)f2b(acc[4] * inv)  | ((unsigned)f2b(acc[5] * inv)  << 16);
            o0.w = (unsigned)f2b(acc[6] * inv)  | ((unsigned)f2b(acc[7] * inv)  << 16);
            o1.x = (unsigned)f2b(acc[8] * inv)  | ((unsigned)f2b(acc[9] * inv)  << 16);
            o1.y = (unsigned)f2b(acc[10] * inv) | ((unsigned)f2b(acc[11] * inv) << 16);
            o1.z = (unsigned)f2b(acc[12] * inv) | ((unsigned)f2b(acc[13] * inv) << 16);
            o1.w = (unsigned)f2b(acc[14] * inv) | ((unsigned)f2b(acc[15] * inv) << 16);
            unsigned short* dst = agg + (size_t)node * 128 + f * 16;
            *(uint4*)dst = o0;
            *(uint4*)(dst + 8) = o1;
        }
    }
}

// GEMM: out[i,:] = (agg||x)@Wt^T + bias (+ReLU). 64-row tiles, 4 waves.
// Layouts (m89/m120-verified): A[m=lane&15][k=quad*8+j],
// B[n=lane&15][k=quad*8+j], C/D col=lane&15, row=quad*4+reg.
// OUT_BF16=1 may alias Xrow (tiles row-disjoint; rows staged to LDS first).
// WF8=1 additionally writes fp8 shadow (f8out).
template<int RELU, int OUT_BF16, int WF8>
static __device__ void gemm_phase(const unsigned short* __restrict__ Arow,
                                  const unsigned short* __restrict__ Xrow,
                                  const unsigned short* __restrict__ Wt,
                                  const float* __restrict__ bias,
                                  void* __restrict__ outp,
                                  unsigned char* __restrict__ f8out, int N,
                                  unsigned short* sA, int bid, int nblocks) {
    int tid = threadIdx.x;
    int ntiles = (N + 63) >> 6;
    for (int t = bid; t < ntiles; t += nblocks) {
        int row0 = t * 64;
        #pragma unroll
        for (int it = 0; it < 8; ++it) {
            int c = tid + it * 256;
            int r = c >> 5;
            int q = c & 31;
            int row = row0 + r; if (row >= N) row = N - 1;
            uint4 v = (q < 16) ? ((const uint4*)(Arow + (size_t)row * 128))[q]
                               : ((const uint4*)(Xrow + (size_t)row * 128))[q - 16];
            *(uint4*)&sA[r * LDK + q * 8] = v;
        }
        __syncthreads();

        int lane = tid & 63;
        int wave = tid >> 6;
        int quad = lane >> 4;
        int tm   = lane & 15;

        f32x4 acc[4][2];
        #pragma unroll
        for (int m = 0; m < 4; ++m)
            #pragma unroll
            for (int j = 0; j < 2; ++j)
                acc[m][j] = (f32x4){0.f, 0.f, 0.f, 0.f};

        const unsigned short* wb0 = Wt + (size_t)(wave * 32 + tm) * 256;

        #pragma unroll
        for (int ks = 0; ks < 8; ++ks) {
            int k0 = ks * 32 + quad * 8;
            bf16x8 a[4], b[2];
            #pragma unroll
            for (int m = 0; m < 4; ++m)
                a[m] = *(const bf16x8*)&sA[(m * 16 + tm) * LDK + k0];
            #pragma unroll
            for (int j = 0; j < 2; ++j)
                b[j] = *(const bf16x8*)(wb0 + (size_t)j * 16 * 256 + k0);
            #pragma unroll
            for (int m = 0; m < 4; ++m)
                #pragma unroll
                for (int j = 0; j < 2; ++j)
                    acc[m][j] = __builtin_amdgcn_mfma_f32_16x16x32_bf16(a[m], b[j], acc[m][j], 0, 0, 0);
        }

        #pragma unroll
        for (int j = 0; j < 2; ++j) {
            int ncol = wave * 32 + j * 16 + tm;
            float bb = bias[ncol];
            #pragma unroll
            for (int m = 0; m < 4; ++m) {
                #pragma unroll
                for (int reg = 0; reg < 4; ++reg) {
                    int row = row0 + m * 16 + quad * 4 + reg;
                    if (row >= N) continue;
                    float v = acc[m][j][reg] + bb;
                    if (RELU) v = v > 0.f ? v : 0.f;
                    if (OUT_BF16)
                        ((unsigned short*)outp)[(size_t)row * 128 + ncol] = f2b(v);
                    else
                        ((float*)outp)[(size_t)row * 128 + ncol] = v;
                    if (WF8)
                        f8out[(size_t)row * 128 + ncol] = f2f8(v);
                }
            }
        }
        __syncthreads();   // LDS reuse across grid-stride iterations
    }
}

// ===========================================================================
// Cooperative mega-kernel: all phases, grid.sync() between them.
// Grid size chosen at launch from occupancy query (any multiple of 8 works).
// ===========================================================================
extern "C" __global__ void __launch_bounds__(256, 4) mega_kernel(
        const float* __restrict__ x, const int* __restrict__ ei,
        const float* __restrict__ W1l, const float* __restrict__ b1,
        const float* __restrict__ W1r, const float* __restrict__ W2l,
        const float* __restrict__ b2, const float* __restrict__ W2r,
        float* __restrict__ out, int* __restrict__ cursor,
        unsigned short* __restrict__ edge16, unsigned short* __restrict__ agg_bf,
        unsigned short* __restrict__ xb, unsigned char* __restrict__ xf8,
        unsigned short* __restrict__ wt, int N, int E) {
    __shared__ unsigned short sA[64 * LDK];
    cg::grid_group grid = cg::this_grid();
    int nb = gridDim.x;
    int bid = blockIdx.x;
    int T = nb * 256;
    int t0 = bid * 256 + threadIdx.x;

    prep_phase(x, xb, xf8, cursor, W1l, W1r, W2l, W2r, wt, N, T, t0);
    grid.sync();
    fill_phase(ei, cursor, edge16, E, N, bid, nb);
    grid.sync();
    agg_phase(xf8, cursor, edge16, ei, agg_bf, E, N, bid, nb);
    grid.sync();
    // gemm1: h(bf16) -> xb (row-disjoint tiles), fp8 shadow -> xf8 (dead)
    gemm_phase<1, 1, 1>(agg_bf, xb, wt, b1, (void*)xb, xf8, N, sA, bid, nb);
    grid.sync();
    agg_phase(xf8, cursor, edge16, ei, agg_bf, E, N, bid, nb);
    grid.sync();
    gemm_phase<0, 0, 0>(agg_bf, xb, wt + 32768, b2, (void*)out, nullptr, N, sA, bid, nb);
}

// ===========================================================================
// Split fallback wrappers (identical math; used if cooperative launch fails)
// ===========================================================================
__global__ __launch_bounds__(256) void k_prep(
        const float* __restrict__ x, unsigned short* __restrict__ xb,
        unsigned char* __restrict__ xf8, int* __restrict__ cursor,
        const float* __restrict__ W1l, const float* __restrict__ W1r,
        const float* __restrict__ W2l, const float* __restrict__ W2r,
        unsigned short* __restrict__ wt, int N) {
    int T = gridDim.x * 256;
    int t0 = blockIdx.x * 256 + threadIdx.x;
    prep_phase(x, xb, xf8, cursor, W1l, W1r, W2l, W2r, wt, N, T, t0);
}

__global__ __launch_bounds__(256) void k_fill(
        const int* __restrict__ ei, int* __restrict__ cursor,
        unsigned short* __restrict__ edge16, int E, int N) {
    fill_phase(ei, cursor, edge16, E, N, blockIdx.x, gridDim.x);
}

__global__ __launch_bounds__(256) void k_agg(
        const unsigned char* __restrict__ in8, const int* __restrict__ cursor,
        const unsigned short* __restrict__ edge16, const int* __restrict__ ei,
        unsigned short* __restrict__ agg, int E, int N) {
    agg_phase(in8, cursor, edge16, ei, agg, E, N, blockIdx.x, gridDim.x);
}

template<int RELU, int OUT_BF16, int WF8>
__global__ __launch_bounds__(256) void k_gemm(
        const unsigned short* __restrict__ Arow, const unsigned short* __restrict__ Xrow,
        const unsigned short* __restrict__ Wt, const float* __restrict__ bias,
        void* __restrict__ outp, unsigned char* __restrict__ f8out, int N) {
    __shared__ unsigned short sA[64 * LDK];
    gemm_phase<RELU, OUT_BF16, WF8>(Arow, Xrow, Wt, bias, outp, f8out, N, sA,
                                    blockIdx.x, gridDim.x);
}

// ---------------------------------------------------------------------------
extern "C" void kernel_launch(void* const* d_in, const int* in_sizes, int n_in,
                              void* d_out, int out_size, void* d_ws, size_t ws_size,
                              hipStream_t stream) {
    const float* x   = (const float*)d_in[0];
    const int*   ei  = (const int*)d_in[1];     // int32 (harness converts int64)
    const float* W1l = (const float*)d_in[2];
    const float* b1  = (const float*)d_in[3];
    const float* W1r = (const float*)d_in[4];
    const float* W2l = (const float*)d_in[5];
    const float* b2  = (const float*)d_in[6];
    const float* W2r = (const float*)d_in[7];
    float* out = (float*)d_out;

    const int D = 128;
    int N = in_sizes[0] / D;     // 50000
    int E = in_sizes[1] / 2;     // 800000

    // workspace carve-out (512B aligned), ~39 MB total
    char* ws = (char*)d_ws;
    size_t off = 0;
    auto alloc = [&](size_t bytes) {
        size_t o = off;
        off = (off + bytes + 511) & ~(size_t)511;
        return (void*)(ws + o);
    };
    int*            cursor  = (int*)           alloc((size_t)N * 4);
    unsigned short* edge16  = (unsigned short*)alloc((size_t)N * CAP * 2);
    unsigned short* agg_bf  = (unsigned short*)alloc((size_t)N * D * 2);
    unsigned short* xb      = (unsigned short*)alloc((size_t)N * D * 2);
    unsigned char*  xf8     = (unsigned char*) alloc((size_t)N * D);
    unsigned short* wt      = (unsigned short*)alloc((size_t)2 * 128 * 256 * 2);
    (void)ws_size; (void)n_in; (void)out_size;

    // --- size the cooperative grid from the occupancy query (never assume) ---
    int dev = 0;
    hipGetDevice(&dev);
    int nCU = 256;
    hipDeviceGetAttribute(&nCU, hipDeviceAttributeMultiprocessorCount, dev);
    int perCU = 0;
    hipError_t qerr = hipOccupancyMaxActiveBlocksPerMultiprocessor(
        &perCU, (const void*)mega_kernel, 256, 0);
    long cap = (qerr == hipSuccess) ? (long)perCU * nCU : 0;
    int grid = (int)(cap < 1024 ? cap : 1024);
    grid &= ~7;                                  // fill_phase needs multiple of 8

    hipError_t err = hipErrorUnknown;
    if (grid >= 8) {
        void* args[] = {
            (void*)&x, (void*)&ei, (void*)&W1l, (void*)&b1, (void*)&W1r,
            (void*)&W2l, (void*)&b2, (void*)&W2r, (void*)&out,
            (void*)&cursor, (void*)&edge16, (void*)&agg_bf, (void*)&xb,
            (void*)&xf8, (void*)&wt, (void*)&N, (void*)&E
        };
        err = hipLaunchCooperativeKernel((void*)mega_kernel, dim3(grid), dim3(256),
                                         args, 0, stream);
    }

    if (err != hipSuccess) {
        // ---- split fallback: 6 dispatches, identical math ----
        k_prep<<<1024, 256, 0, stream>>>(x, xb, xf8, cursor, W1l, W1r, W2l, W2r, wt, N);
        k_fill<<<2048, 256, 0, stream>>>(ei, cursor, edge16, E, N);
        int agg_grid = (N + 3) / 4;
        int gemm_grid = (N + 63) / 64;
        k_agg<<<agg_grid, 256, 0, stream>>>(xf8, cursor, edge16, ei, agg_bf, E, N);
        k_gemm<1, 1, 1><<<gemm_grid, 256, 0, stream>>>(agg_bf, xb, wt, b1, (void*)xb, xf8, N);
        k_agg<<<agg_grid, 256, 0, stream>>>(xf8, cursor, edge16, ei, agg_bf, E, N);
        k_gemm<0, 0, 0><<<gemm_grid, 256, 0, stream>>>(agg_bf, xb, wt + 32768, b2, (void*)out, nullptr, N);
    }
}